// Round 11
// baseline (102.335 us; speedup 1.0000x reference)
//
#include <hip/hip_runtime.h>
#include <hip/hip_bf16.h>

// LineCNNSimple: 1024 x (conv3x3 1->64 +relu, conv3x3 64->64 +relu, maxpool2,
// fc 12544->128 +relu, fc 128->83). bf16 MFMA pipeline.
// R11: conv = R7-clean (73.5us best) + setprio. prep: wfc1 repack INVERTED
//      (coalesced contiguous reads, scattered 2B writes; L2 merges) — the
//      old mapping line-amplified 6.4MB of reads into ~20MB.
//
// ws element(u16) offsets:
//   WB1  @0        : 2048    conv1 W frag [4nt][64lane][8], k==9 slot = bias
//   WB2  @2048     : 36864   conv2 W frag [2nh][36ks][64lane][8], k=(dy*3+dx)*64+ci
//   WFC1 @38912    : 1605632 fc1 W frag [8nt][392ks][64lane][8], k'=(oyp*14+oxp)*64+co
//   WFC2 @1644544  : 12288   fc2 W frag [6nt][4ks][64lane][8] (cls>=83 zeroed)
//   POOL @1656832  : 12845056 pooled acts [1024][12544] bf16 (k'-order)
//   PART @byte 29003776 : f16 fc1 partials [4q][64ig][16img][128fcn] (1MB)

typedef __attribute__((ext_vector_type(8))) short short8;
typedef __attribute__((ext_vector_type(4))) float f32x4;
typedef __attribute__((ext_vector_type(16))) float f32x16;

#define WB1_E   0u
#define WB2_E   2048u
#define WFC1_E  38912u
#define WFC2_E  1644544u
#define POOL_E  1656832u
#define PART_B  29003776u

__device__ __forceinline__ unsigned short f2bf(float f) {
  unsigned u = __float_as_uint(f);
  u += 0x7fffu + ((u >> 16) & 1u);   // round-to-nearest-even
  return (unsigned short)(u >> 16);
}
// pack two f32 -> bf16 pair (lo = a, hi = b), RNE, single instruction
__device__ __forceinline__ unsigned cvtpk_bf16(float a, float b) {
  unsigned r;
  asm("v_cvt_pk_bf16_f32 %0, %1, %2" : "=v"(r) : "v"(a), "v"(b));
  return r;
}

// ---------------- prep: repack weights to bf16 frag order ----------------
// wfc1 branch is INVERSE-mapped: thread i reads contiguous wfc1[i] (coalesced),
// computes scattered ws16 destination. Other branches forward-mapped (small).
__global__ __launch_bounds__(256) void prep_kernel(
    const float* __restrict__ w1, const float* __restrict__ c1b,
    const float* __restrict__ w2, const float* __restrict__ wfc1,
    const float* __restrict__ wfc2, unsigned short* __restrict__ ws16)
{
  int i = blockIdx.x * blockDim.x + threadIdx.x;
  if (i < 2048) {
    int j = i & 7, l = (i >> 3) & 63, nt = i >> 9;
    int n = nt * 16 + (l & 15), k = 8 * (l >> 4) + j;
    float v = (k < 9) ? w1[n * 9 + k] : (k == 9 ? c1b[n] : 0.f);
    ws16[WB1_E + i] = f2bf(v);
  } else if (i < 38912) {
    int i2 = i - 2048;                // conv2 W for 32x32x16 MFMA
    int j = i2 & 7, l = (i2 >> 3) & 63, rest = i2 >> 9;
    int ks = rest % 36, nh = rest / 36;
    int co = nh * 32 + (l & 31);
    int k = ks * 16 + (l >> 5) * 8 + j;
    int dydx = k >> 6, ci = k & 63;
    ws16[WB2_E + i2] = f2bf(w2[co * 576 + ci * 9 + dydx]);
  } else if (i < 1644544) {
    int i2 = i - 38912;               // INVERSE map: i2 = flat wfc1 index
    int fcn = i2 / 12544;
    int r = i2 - fcn * 12544;
    int co = r / 196;
    int sp = r - co * 196;            // = oyp*14+oxp
    int kp = sp * 64 + co;            // k' (sp-major)
    int ks = kp >> 5, kk = kp & 31;
    int g = kk >> 3, j = kk & 7;
    int nt = fcn >> 4;
    int l = (g << 4) | (fcn & 15);
    ws16[WFC1_E + (((nt * 392 + ks) * 64 + l) << 3) + j] = f2bf(wfc1[i2]);
  } else if (i < 1656832) {
    int i2 = i - 1644544;             // forward map (tiny; zero-fills cls>=83)
    int j = i2 & 7, l = (i2 >> 3) & 63, rest = i2 >> 9;
    int ks = rest & 3, nt = rest >> 2;
    int cls = nt * 16 + (l & 15);
    int k = ks * 32 + 8 * (l >> 4) + j;
    float v = (cls < 83) ? wfc2[cls * 128 + k] : 0.f;
    ws16[WFC2_E + i2] = f2bf(v);
  }
}

// ---------------- fused conv1+conv2+pool; one (image, row-half) per block ----
// lds1: [18 rows][30 cols] cells x 144 B (64 u16 co + 8 u16 pad) = 77,760 B
// xw:   padded 30x30 bf16 input @ 77760, 1800 B
__global__ __launch_bounds__(512, 4) void conv_kernel(
    const float* __restrict__ x, const float* __restrict__ c2b,
    unsigned short* __restrict__ ws16)
{
  extern __shared__ char smem[];
  unsigned short* xw = (unsigned short*)(smem + 77760);

  const int tid = threadIdx.x;
  const int wave = tid >> 6, lane = tid & 63;
  const int bid = blockIdx.x;
  const int n = bid >> 1, hf = bid & 1;
  const int rlo = hf ? 15 : 0;          // first conv1 output row this half
  const int M1 = hf ? 364 : 476;        // conv1 positions this half
  const int T1 = hf ? 23 : 30;          // conv1 16-tiles (ceil)
  const int lr_off = hf ? -15 : 1;      // conv1 store row: lr = rr + lr_off

  const short8* wb1 = (const short8*)(ws16 + WB1_E);
  unsigned short* poolg = ws16 + POOL_E + (unsigned)n * 12544u;

  short8 z8 = {0, 0, 0, 0, 0, 0, 0, 0};
  // zero lds1 (incl pads); stage padded window (bounds folded in)
  {
    short8* l8 = (short8*)smem;
    for (int idx = tid; idx < 4860; idx += 512) l8[idx] = z8;
    const float* xg = x + (n >> 5) * 25088 + (n & 31) * 28;
    for (int i = tid; i < 900; i += 512) {
      int yy = (i * 2185) >> 16;        // i/30
      int xx = i - yy * 30;
      int iy = yy - 1, ix = xx - 1;
      bool inb = (iy >= 0) && (iy < 28) && (ix >= 0) && (ix < 28);
      float v = inb ? xg[iy * 896 + ix] : 0.f;
      xw[i] = f2bf(v);
    }
  }
  __syncthreads();

  // ---- conv1 (16x16x32): weights as A-operand; compile-time LDS offsets
  {
    const int g = lane >> 4, l15 = lane & 15;
    short8 b1f[4];
#pragma unroll
    for (int nt = 0; nt < 4; ++nt) b1f[nt] = wb1[nt * 64 + lane];
    for (int mt = wave; mt < T1; mt += 8) {
      int m = mt * 16 + l15;
      bool mval = m < M1;
      int mc = mval ? m : M1 - 1;
      int yr = (mc * 2341) >> 16;       // mc/28
      int rr = rlo + yr;
      int ox = mc - yr * 28;
      const char* xb = (const char*)xw + (rr * 30 + ox) * 2;
      short8 a = z8;
      if (g == 0) {                     // k = 0..7  (dy*3+dx)
        a[0] = *(const short*)(xb + 0);
        a[1] = *(const short*)(xb + 2);
        a[2] = *(const short*)(xb + 4);
        a[3] = *(const short*)(xb + 60);
        a[4] = *(const short*)(xb + 62);
        a[5] = *(const short*)(xb + 64);
        a[6] = *(const short*)(xb + 120);
        a[7] = *(const short*)(xb + 122);
      } else if (g == 1) {              // k = 8, k = 9 bias lane
        a[0] = *(const short*)(xb + 124);
        a[1] = (short)0x3F80;           // 1.0 bf16
      }
      f32x4 d[4];
#pragma unroll
      for (int nt = 0; nt < 4; ++nt) {
        f32x4 zz = {0.f, 0.f, 0.f, 0.f};
        d[nt] = __builtin_amdgcn_mfma_f32_16x16x32_bf16(b1f[nt], a, zz, 0, 0, 0);
      }
      if (mval) {                       // D: row=co 4g+i, col=own l15 -> m
        int spB = ((rr + lr_off) * 30 + ox + 1) * 144;
#pragma unroll
        for (int nt = 0; nt < 4; ++nt) {
          float r0 = fmaxf(d[nt][0], 0.f), r1 = fmaxf(d[nt][1], 0.f);
          float r2 = fmaxf(d[nt][2], 0.f), r3 = fmaxf(d[nt][3], 0.f);
          int co2 = nt * 16 + 4 * g;
          *(unsigned*)(smem + (spB + co2 * 2)) = cvtpk_bf16(r0, r1);
          *(unsigned*)(smem + (spB + co2 * 2 + 4)) = cvtpk_bf16(r2, r3);
        }
      }
    }
  }
  __syncthreads();

  // ---- conv2 (32x32x16): wave owns tiles (wave, wave+8) x both co-halves.
  // Raw s_barrier per phase-pair aligns all 8 waves' B-loads (L1 sharing);
  // s_setprio(1) around MFMA clusters.
  {
    const int l31 = lane & 31;
    const int h = lane >> 5;
    const int T32 = hf ? 11 : 14;       // M-tiles this half
    const int Wh  = hf ? 84 : 112;      // valid windows this half
    const float bias0 = c2b[l31];
    const float bias1 = c2b[32 + l31];
    const short8* wb2w = (const short8*)(ws16 + WB2_E) + lane;

    const bool v1 = (wave + 8) < T32;
    int baseB0, baseB1;
    {
      int lw = wave * 8 + (l31 >> 2);
      int py = lw / 14, px = lw % 14;
      baseB0 = ((2 * py + ((l31 >> 1) & 1)) * 30 + 2 * px + (l31 & 1)) * 144 + h * 16;
      int tI1 = v1 ? (wave + 8) : wave;  // clamp (unused when !v1)
      int lw1 = tI1 * 8 + (l31 >> 2);
      int py1 = lw1 / 14, px1 = lw1 % 14;
      baseB1 = ((2 * py1 + ((l31 >> 1) & 1)) * 30 + 2 * px1 + (l31 & 1)) * 144 + h * 16;
    }
    f32x16 acc00 = (f32x16)(0.0f), acc01 = (f32x16)(0.0f);
    f32x16 acc10 = (f32x16)(0.0f), acc11 = (f32x16)(0.0f);

    short8 bfA0, bfA1, bfA2, bfA3;      // ping (nh0 k0, nh0 k1, nh1 k0, nh1 k1)
    short8 bfB0, bfB1, bfB2, bfB3;      // pong

#define LOADB(d0, d1, d2, d3, hp) do {                                   \
      const int ph_ = (hp) >> 1, k0_ = ((hp) & 1) * 2;                   \
      d0 = wb2w[(ph_ * 4 + k0_) * 64];                                   \
      d1 = wb2w[(ph_ * 4 + k0_ + 1) * 64];                               \
      d2 = wb2w[2304 + (ph_ * 4 + k0_) * 64];                            \
      d3 = wb2w[2304 + (ph_ * 4 + k0_ + 1) * 64];                        \
    } while (0)
#define COMPT(hp, base, aL, aH, b0, b1, b2, b3) do {                     \
      const int ph_ = (hp) >> 1, k0_ = ((hp) & 1) * 2;                   \
      const int cell_ = ((ph_ / 3) * 30 + (ph_ % 3)) * 144 + 32 * k0_;   \
      short8 a0 = *(const short8*)(smem + (base + cell_));               \
      short8 a1 = *(const short8*)(smem + (base + cell_ + 32));          \
      aL = __builtin_amdgcn_mfma_f32_32x32x16_bf16(a0, b0, aL, 0, 0, 0); \
      aH = __builtin_amdgcn_mfma_f32_32x32x16_bf16(a0, b2, aH, 0, 0, 0); \
      aL = __builtin_amdgcn_mfma_f32_32x32x16_bf16(a1, b1, aL, 0, 0, 0); \
      aH = __builtin_amdgcn_mfma_f32_32x32x16_bf16(a1, b3, aH, 0, 0, 0); \
    } while (0)

    LOADB(bfA0, bfA1, bfA2, bfA3, 0);
    if (v1) {
#pragma unroll
      for (int hp = 0; hp < 18; hp += 2) {
        __builtin_amdgcn_s_barrier();   // align waves' B-loads (no waitcnt)
        if (hp + 1 < 18) LOADB(bfB0, bfB1, bfB2, bfB3, hp + 1);
        __builtin_amdgcn_s_setprio(1);
        COMPT(hp, baseB0, acc00, acc01, bfA0, bfA1, bfA2, bfA3);
        COMPT(hp, baseB1, acc10, acc11, bfA0, bfA1, bfA2, bfA3);
        __builtin_amdgcn_s_setprio(0);
        if (hp + 2 < 18) LOADB(bfA0, bfA1, bfA2, bfA3, hp + 2);
        __builtin_amdgcn_s_setprio(1);
        COMPT(hp + 1, baseB0, acc00, acc01, bfB0, bfB1, bfB2, bfB3);
        COMPT(hp + 1, baseB1, acc10, acc11, bfB0, bfB1, bfB2, bfB3);
        __builtin_amdgcn_s_setprio(0);
      }
    } else {
#pragma unroll
      for (int hp = 0; hp < 18; hp += 2) {
        __builtin_amdgcn_s_barrier();
        if (hp + 1 < 18) LOADB(bfB0, bfB1, bfB2, bfB3, hp + 1);
        __builtin_amdgcn_s_setprio(1);
        COMPT(hp, baseB0, acc00, acc01, bfA0, bfA1, bfA2, bfA3);
        __builtin_amdgcn_s_setprio(0);
        if (hp + 2 < 18) LOADB(bfA0, bfA1, bfA2, bfA3, hp + 2);
        __builtin_amdgcn_s_setprio(1);
        COMPT(hp + 1, baseB0, acc00, acc01, bfB0, bfB1, bfB2, bfB3);
        __builtin_amdgcn_s_setprio(0);
      }
    }
#undef LOADB
#undef COMPT

    // epilogue: 2x2 max + bias + relu -> global (bf16, fc1 k'-order)
#pragma unroll
    for (int q = 0; q < 4; ++q) {
      int lw0 = wave * 8 + 2 * q + h;
      {
        float p0 = fmaxf(fmaxf(acc00[4 * q], acc00[4 * q + 1]),
                         fmaxf(acc00[4 * q + 2], acc00[4 * q + 3]));
        float p1 = fmaxf(fmaxf(acc01[4 * q], acc01[4 * q + 1]),
                         fmaxf(acc01[4 * q + 2], acc01[4 * q + 3]));
        unsigned pk = cvtpk_bf16(fmaxf(p0 + bias0, 0.f), fmaxf(p1 + bias1, 0.f));
        poolg[(hf * 112 + lw0) * 64 + l31]      = (unsigned short)pk;
        poolg[(hf * 112 + lw0) * 64 + 32 + l31] = (unsigned short)(pk >> 16);
      }
      if (v1) {
        int lw1 = (wave + 8) * 8 + 2 * q + h;
        if (lw1 < Wh) {
          float p0 = fmaxf(fmaxf(acc10[4 * q], acc10[4 * q + 1]),
                           fmaxf(acc10[4 * q + 2], acc10[4 * q + 3]));
          float p1 = fmaxf(fmaxf(acc11[4 * q], acc11[4 * q + 1]),
                           fmaxf(acc11[4 * q + 2], acc11[4 * q + 3]));
          unsigned pk = cvtpk_bf16(fmaxf(p0 + bias0, 0.f), fmaxf(p1 + bias1, 0.f));
          poolg[(hf * 112 + lw1) * 64 + l31]      = (unsigned short)pk;
          poolg[(hf * 112 + lw1) * 64 + 32 + l31] = (unsigned short)(pk >> 16);
        }
      }
    }
  }
}

// ---------------- fc1 stage A: 256 blocks = 64 img-groups x 4 K-slices ----
// 4-deep B-prefetch ring; over-reads past q-slice end are benign (discarded).
__global__ __launch_bounds__(512) void fc1_kernel(unsigned short* __restrict__ ws16)
{
  extern __shared__ char smem[];
  short8* A8 = (short8*)smem;              // [16 img][393 short8] (stride pad)
  const int tid = threadIdx.x;
  const int wave = tid >> 6, lane = tid & 63;
  const int g = lane >> 4, l15 = lane & 15;
  const int ig = blockIdx.x >> 2, q = blockIdx.x & 3;
  const short8* pool8 = (const short8*)(ws16 + POOL_E);
  const short8* wf1 = (const short8*)(ws16 + WFC1_E);
  {
    int img = tid >> 5, l32 = tid & 31;
    const short8* src = pool8 + (ig * 16 + img) * 1568 + q * 392;
#pragma unroll
    for (int j = 0; j < 13; ++j) {
      int idx = l32 + 32 * j;
      if (idx < 392) A8[img * 393 + idx] = src[idx];
    }
  }
  __syncthreads();
  f32x4 accA = {0.f, 0.f, 0.f, 0.f}, accB = {0.f, 0.f, 0.f, 0.f};
  const short8* wbase = wf1 + (wave * 392 + q * 98) * 64 + lane;
  short8 bP0 = wbase[0 * 64], bP1 = wbase[1 * 64];
  short8 bP2 = wbase[2 * 64], bP3 = wbase[3 * 64];
#pragma unroll 1
  for (int c = 0; c < 24; ++c) {           // ks = 4c .. 4c+3 ; prefetch 4 ahead
    int ks = 4 * c;
    short8 a;
    a = A8[l15 * 393 + (ks + 0) * 4 + g];
    accA = __builtin_amdgcn_mfma_f32_16x16x32_bf16(a, bP0, accA, 0, 0, 0);
    bP0 = wbase[(ks + 4) * 64];
    a = A8[l15 * 393 + (ks + 1) * 4 + g];
    accB = __builtin_amdgcn_mfma_f32_16x16x32_bf16(a, bP1, accB, 0, 0, 0);
    bP1 = wbase[(ks + 5) * 64];
    a = A8[l15 * 393 + (ks + 2) * 4 + g];
    accA = __builtin_amdgcn_mfma_f32_16x16x32_bf16(a, bP2, accA, 0, 0, 0);
    bP2 = wbase[(ks + 6) * 64];
    a = A8[l15 * 393 + (ks + 3) * 4 + g];
    accB = __builtin_amdgcn_mfma_f32_16x16x32_bf16(a, bP3, accB, 0, 0, 0);
    bP3 = wbase[(ks + 7) * 64];
  }
  {                                        // tail ks = 96, 97
    short8 a;
    a = A8[l15 * 393 + 96 * 4 + g];
    accA = __builtin_amdgcn_mfma_f32_16x16x32_bf16(a, bP0, accA, 0, 0, 0);
    a = A8[l15 * 393 + 97 * 4 + g];
    accB = __builtin_amdgcn_mfma_f32_16x16x32_bf16(a, bP1, accB, 0, 0, 0);
  }
  _Float16* part = (_Float16*)((char*)ws16 + PART_B);
  int base = ((q * 64 + ig) * 16 + 4 * g) * 128 + wave * 16 + l15;
#pragma unroll
  for (int i = 0; i < 4; ++i) part[base + i * 128] = (_Float16)(accA[i] + accB[i]);
}

// ---------------- fc stage B: sum 4 partials + bias/relu + fc2 ----
__global__ __launch_bounds__(512) void fc2_kernel(
    const float* __restrict__ b1, const float* __restrict__ b2,
    const unsigned short* __restrict__ ws16, float* __restrict__ out)
{
  __shared__ unsigned short h_s[16 * 136];
  const int tid = threadIdx.x;
  const int wave = tid >> 6, lane = tid & 63;
  const int g = lane >> 4, l15 = lane & 15;
  const int ig = blockIdx.x;
  const _Float16* part = (const _Float16*)((const char*)ws16 + PART_B);
#pragma unroll
  for (int t = 0; t < 4; ++t) {
    int u = tid + 512 * t;
    int img = u >> 7, fcn = u & 127;
    float s = 0.f;
#pragma unroll
    for (int q2 = 0; q2 < 4; ++q2)
      s += (float)part[((q2 * 64 + ig) * 16 + img) * 128 + fcn];
    h_s[img * 136 + fcn] = f2bf(fmaxf(s + b1[fcn], 0.f));
  }
  __syncthreads();
  if (wave < 6) {
    const short8* wf2 = (const short8*)(ws16 + WFC2_E);
    const short8* h8 = (const short8*)h_s;
    f32x4 a2 = {0.f, 0.f, 0.f, 0.f};
#pragma unroll
    for (int ks = 0; ks < 4; ++ks) {
      short8 b = wf2[(wave * 4 + ks) * 64 + lane];
      short8 a = h8[l15 * 17 + ks * 4 + g];
      a2 = __builtin_amdgcn_mfma_f32_16x16x32_bf16(a, b, a2, 0, 0, 0);
    }
    int cls = wave * 16 + l15;
    if (cls < 83) {
      float bias2 = b2[cls];
#pragma unroll
      for (int i = 0; i < 4; ++i) {
        int nimg = ig * 16 + 4 * g + i;
        out[((nimg >> 5) * 83 + cls) * 32 + (nimg & 31)] = a2[i] + bias2;
      }
    }
  }
}

extern "C" void kernel_launch(void* const* d_in, const int* in_sizes, int n_in,
                              void* d_out, int out_size, void* d_ws, size_t ws_size,
                              hipStream_t stream)
{
  const float* x    = (const float*)d_in[0];
  const float* w1   = (const float*)d_in[1];
  const float* c1b  = (const float*)d_in[2];
  const float* w2   = (const float*)d_in[3];
  const float* c2b  = (const float*)d_in[4];
  const float* wfc1 = (const float*)d_in[5];
  const float* bfc1 = (const float*)d_in[6];
  const float* wfc2 = (const float*)d_in[7];
  const float* bfc2 = (const float*)d_in[8];
  unsigned short* ws16 = (unsigned short*)d_ws;
  float* out = (float*)d_out;

  prep_kernel<<<6472, 256, 0, stream>>>(w1, c1b, w2, wfc1, wfc2, ws16);
  conv_kernel<<<2048, 512, 79616, stream>>>(x, c2b, ws16);
  fc1_kernel<<<256, 512, 100608, stream>>>(ws16);
  fc2_kernel<<<64, 512, 0, stream>>>(bfc1, bfc2, ws16, out);
}

// Round 12
// 91.469 us; speedup vs baseline: 1.1188x; 1.1188x over previous
//
#include <hip/hip_runtime.h>
#include <hip/hip_bf16.h>

// LineCNNSimple: 1024 x (conv3x3 1->64 +relu, conv3x3 64->64 +relu, maxpool2,
// fc 12544->128 +relu, fc 128->83). bf16 MFMA pipeline.
// R12: best-known config. conv = R7-clean (73.5us; no setprio — measured -3us),
//      prep = R7 forward map (inverse map cost +4.3us), fc1 B-ring 4->8 deep.
//
// ws element(u16) offsets:
//   WB1  @0        : 2048    conv1 W frag [4nt][64lane][8], k==9 slot = bias
//   WB2  @2048     : 36864   conv2 W frag [2nh][36ks][64lane][8], k=(dy*3+dx)*64+ci
//   WFC1 @38912    : 1605632 fc1 W frag [8nt][392ks][64lane][8], k'=(oyp*14+oxp)*64+co
//   WFC2 @1644544  : 12288   fc2 W frag [6nt][4ks][64lane][8] (cls>=83 zeroed)
//   POOL @1656832  : 12845056 pooled acts [1024][12544] bf16 (k'-order)
//   PART @byte 29003776 : f16 fc1 partials [4q][64ig][16img][128fcn] (1MB)

typedef __attribute__((ext_vector_type(8))) short short8;
typedef __attribute__((ext_vector_type(4))) float f32x4;
typedef __attribute__((ext_vector_type(16))) float f32x16;

#define WB1_E   0u
#define WB2_E   2048u
#define WFC1_E  38912u
#define WFC2_E  1644544u
#define POOL_E  1656832u
#define PART_B  29003776u

__device__ __forceinline__ unsigned short f2bf(float f) {
  unsigned u = __float_as_uint(f);
  u += 0x7fffu + ((u >> 16) & 1u);   // round-to-nearest-even
  return (unsigned short)(u >> 16);
}
// pack two f32 -> bf16 pair (lo = a, hi = b), RNE, single instruction
__device__ __forceinline__ unsigned cvtpk_bf16(float a, float b) {
  unsigned r;
  asm("v_cvt_pk_bf16_f32 %0, %1, %2" : "=v"(r) : "v"(a), "v"(b));
  return r;
}

// ---------------- prep: repack weights to bf16 frag order (forward map) ----
__global__ __launch_bounds__(256) void prep_kernel(
    const float* __restrict__ w1, const float* __restrict__ c1b,
    const float* __restrict__ w2, const float* __restrict__ wfc1,
    const float* __restrict__ wfc2, unsigned short* __restrict__ ws16)
{
  int i = blockIdx.x * blockDim.x + threadIdx.x;
  if (i < 2048) {
    int j = i & 7, l = (i >> 3) & 63, nt = i >> 9;
    int n = nt * 16 + (l & 15), k = 8 * (l >> 4) + j;
    float v = (k < 9) ? w1[n * 9 + k] : (k == 9 ? c1b[n] : 0.f);
    ws16[WB1_E + i] = f2bf(v);
  } else if (i < 38912) {
    int i2 = i - 2048;                // conv2 W for 32x32x16 MFMA
    int j = i2 & 7, l = (i2 >> 3) & 63, rest = i2 >> 9;
    int ks = rest % 36, nh = rest / 36;
    int co = nh * 32 + (l & 31);
    int k = ks * 16 + (l >> 5) * 8 + j;
    int dydx = k >> 6, ci = k & 63;
    ws16[WB2_E + i2] = f2bf(w2[co * 576 + ci * 9 + dydx]);
  } else if (i < 1644544) {
    int i2 = i - 38912;
    int j = i2 & 7, l = (i2 >> 3) & 63, rest = i2 >> 9;
    int ks = rest % 392, nt = rest / 392;
    int fcn = nt * 16 + (l & 15);
    int kp = ks * 32 + 8 * (l >> 4) + j;
    int co = kp & 63, r2 = kp >> 6;
    int oxp = r2 % 14, oyp = r2 / 14;
    ws16[WFC1_E + i2] = f2bf(wfc1[fcn * 12544 + co * 196 + oyp * 14 + oxp]);
  } else if (i < 1656832) {
    int i2 = i - 1644544;
    int j = i2 & 7, l = (i2 >> 3) & 63, rest = i2 >> 9;
    int ks = rest & 3, nt = rest >> 2;
    int cls = nt * 16 + (l & 15);
    int k = ks * 32 + 8 * (l >> 4) + j;
    float v = (cls < 83) ? wfc2[cls * 128 + k] : 0.f;
    ws16[WFC2_E + i2] = f2bf(v);
  }
}

// ---------------- fused conv1+conv2+pool; one (image, row-half) per block ----
// lds1: [18 rows][30 cols] cells x 144 B (64 u16 co + 8 u16 pad) = 77,760 B
// xw:   padded 30x30 bf16 input @ 77760, 1800 B
__global__ __launch_bounds__(512, 4) void conv_kernel(
    const float* __restrict__ x, const float* __restrict__ c2b,
    unsigned short* __restrict__ ws16)
{
  extern __shared__ char smem[];
  unsigned short* xw = (unsigned short*)(smem + 77760);

  const int tid = threadIdx.x;
  const int wave = tid >> 6, lane = tid & 63;
  const int bid = blockIdx.x;
  const int n = bid >> 1, hf = bid & 1;
  const int rlo = hf ? 15 : 0;          // first conv1 output row this half
  const int M1 = hf ? 364 : 476;        // conv1 positions this half
  const int T1 = hf ? 23 : 30;          // conv1 16-tiles (ceil)
  const int lr_off = hf ? -15 : 1;      // conv1 store row: lr = rr + lr_off

  const short8* wb1 = (const short8*)(ws16 + WB1_E);
  unsigned short* poolg = ws16 + POOL_E + (unsigned)n * 12544u;

  short8 z8 = {0, 0, 0, 0, 0, 0, 0, 0};
  // zero lds1 (incl pads); stage padded window (bounds folded in)
  {
    short8* l8 = (short8*)smem;
    for (int idx = tid; idx < 4860; idx += 512) l8[idx] = z8;
    const float* xg = x + (n >> 5) * 25088 + (n & 31) * 28;
    for (int i = tid; i < 900; i += 512) {
      int yy = (i * 2185) >> 16;        // i/30
      int xx = i - yy * 30;
      int iy = yy - 1, ix = xx - 1;
      bool inb = (iy >= 0) && (iy < 28) && (ix >= 0) && (ix < 28);
      float v = inb ? xg[iy * 896 + ix] : 0.f;
      xw[i] = f2bf(v);
    }
  }
  __syncthreads();

  // ---- conv1 (16x16x32): weights as A-operand; compile-time LDS offsets
  {
    const int g = lane >> 4, l15 = lane & 15;
    short8 b1f[4];
#pragma unroll
    for (int nt = 0; nt < 4; ++nt) b1f[nt] = wb1[nt * 64 + lane];
    for (int mt = wave; mt < T1; mt += 8) {
      int m = mt * 16 + l15;
      bool mval = m < M1;
      int mc = mval ? m : M1 - 1;
      int yr = (mc * 2341) >> 16;       // mc/28
      int rr = rlo + yr;
      int ox = mc - yr * 28;
      const char* xb = (const char*)xw + (rr * 30 + ox) * 2;
      short8 a = z8;
      if (g == 0) {                     // k = 0..7  (dy*3+dx)
        a[0] = *(const short*)(xb + 0);
        a[1] = *(const short*)(xb + 2);
        a[2] = *(const short*)(xb + 4);
        a[3] = *(const short*)(xb + 60);
        a[4] = *(const short*)(xb + 62);
        a[5] = *(const short*)(xb + 64);
        a[6] = *(const short*)(xb + 120);
        a[7] = *(const short*)(xb + 122);
      } else if (g == 1) {              // k = 8, k = 9 bias lane
        a[0] = *(const short*)(xb + 124);
        a[1] = (short)0x3F80;           // 1.0 bf16
      }
      f32x4 d[4];
#pragma unroll
      for (int nt = 0; nt < 4; ++nt) {
        f32x4 zz = {0.f, 0.f, 0.f, 0.f};
        d[nt] = __builtin_amdgcn_mfma_f32_16x16x32_bf16(b1f[nt], a, zz, 0, 0, 0);
      }
      if (mval) {                       // D: row=co 4g+i, col=own l15 -> m
        int spB = ((rr + lr_off) * 30 + ox + 1) * 144;
#pragma unroll
        for (int nt = 0; nt < 4; ++nt) {
          float r0 = fmaxf(d[nt][0], 0.f), r1 = fmaxf(d[nt][1], 0.f);
          float r2 = fmaxf(d[nt][2], 0.f), r3 = fmaxf(d[nt][3], 0.f);
          int co2 = nt * 16 + 4 * g;
          *(unsigned*)(smem + (spB + co2 * 2)) = cvtpk_bf16(r0, r1);
          *(unsigned*)(smem + (spB + co2 * 2 + 4)) = cvtpk_bf16(r2, r3);
        }
      }
    }
  }
  __syncthreads();

  // ---- conv2 (32x32x16): wave owns tiles (wave, wave+8) x both co-halves.
  // Raw s_barrier per phase-pair aligns all 8 waves' B-loads (L1 sharing).
  {
    const int l31 = lane & 31;
    const int h = lane >> 5;
    const int T32 = hf ? 11 : 14;       // M-tiles this half
    const int Wh  = hf ? 84 : 112;      // valid windows this half
    const float bias0 = c2b[l31];
    const float bias1 = c2b[32 + l31];
    const short8* wb2w = (const short8*)(ws16 + WB2_E) + lane;

    const bool v1 = (wave + 8) < T32;
    int baseB0, baseB1;
    {
      int lw = wave * 8 + (l31 >> 2);
      int py = lw / 14, px = lw % 14;
      baseB0 = ((2 * py + ((l31 >> 1) & 1)) * 30 + 2 * px + (l31 & 1)) * 144 + h * 16;
      int tI1 = v1 ? (wave + 8) : wave;  // clamp (unused when !v1)
      int lw1 = tI1 * 8 + (l31 >> 2);
      int py1 = lw1 / 14, px1 = lw1 % 14;
      baseB1 = ((2 * py1 + ((l31 >> 1) & 1)) * 30 + 2 * px1 + (l31 & 1)) * 144 + h * 16;
    }
    f32x16 acc00 = (f32x16)(0.0f), acc01 = (f32x16)(0.0f);
    f32x16 acc10 = (f32x16)(0.0f), acc11 = (f32x16)(0.0f);

    short8 bfA0, bfA1, bfA2, bfA3;      // ping (nh0 k0, nh0 k1, nh1 k0, nh1 k1)
    short8 bfB0, bfB1, bfB2, bfB3;      // pong

#define LOADB(d0, d1, d2, d3, hp) do {                                   \
      const int ph_ = (hp) >> 1, k0_ = ((hp) & 1) * 2;                   \
      d0 = wb2w[(ph_ * 4 + k0_) * 64];                                   \
      d1 = wb2w[(ph_ * 4 + k0_ + 1) * 64];                               \
      d2 = wb2w[2304 + (ph_ * 4 + k0_) * 64];                            \
      d3 = wb2w[2304 + (ph_ * 4 + k0_ + 1) * 64];                        \
    } while (0)
#define COMPT(hp, base, aL, aH, b0, b1, b2, b3) do {                     \
      const int ph_ = (hp) >> 1, k0_ = ((hp) & 1) * 2;                   \
      const int cell_ = ((ph_ / 3) * 30 + (ph_ % 3)) * 144 + 32 * k0_;   \
      short8 a0 = *(const short8*)(smem + (base + cell_));               \
      short8 a1 = *(const short8*)(smem + (base + cell_ + 32));          \
      aL = __builtin_amdgcn_mfma_f32_32x32x16_bf16(a0, b0, aL, 0, 0, 0); \
      aH = __builtin_amdgcn_mfma_f32_32x32x16_bf16(a0, b2, aH, 0, 0, 0); \
      aL = __builtin_amdgcn_mfma_f32_32x32x16_bf16(a1, b1, aL, 0, 0, 0); \
      aH = __builtin_amdgcn_mfma_f32_32x32x16_bf16(a1, b3, aH, 0, 0, 0); \
    } while (0)

    LOADB(bfA0, bfA1, bfA2, bfA3, 0);
    if (v1) {
#pragma unroll
      for (int hp = 0; hp < 18; hp += 2) {
        __builtin_amdgcn_s_barrier();   // align waves' B-loads (no waitcnt)
        if (hp + 1 < 18) LOADB(bfB0, bfB1, bfB2, bfB3, hp + 1);
        COMPT(hp, baseB0, acc00, acc01, bfA0, bfA1, bfA2, bfA3);
        COMPT(hp, baseB1, acc10, acc11, bfA0, bfA1, bfA2, bfA3);
        if (hp + 2 < 18) LOADB(bfA0, bfA1, bfA2, bfA3, hp + 2);
        COMPT(hp + 1, baseB0, acc00, acc01, bfB0, bfB1, bfB2, bfB3);
        COMPT(hp + 1, baseB1, acc10, acc11, bfB0, bfB1, bfB2, bfB3);
      }
    } else {
#pragma unroll
      for (int hp = 0; hp < 18; hp += 2) {
        __builtin_amdgcn_s_barrier();
        if (hp + 1 < 18) LOADB(bfB0, bfB1, bfB2, bfB3, hp + 1);
        COMPT(hp, baseB0, acc00, acc01, bfA0, bfA1, bfA2, bfA3);
        if (hp + 2 < 18) LOADB(bfA0, bfA1, bfA2, bfA3, hp + 2);
        COMPT(hp + 1, baseB0, acc00, acc01, bfB0, bfB1, bfB2, bfB3);
      }
    }
#undef LOADB
#undef COMPT

    // epilogue: 2x2 max + bias + relu -> global (bf16, fc1 k'-order)
#pragma unroll
    for (int q = 0; q < 4; ++q) {
      int lw0 = wave * 8 + 2 * q + h;
      {
        float p0 = fmaxf(fmaxf(acc00[4 * q], acc00[4 * q + 1]),
                         fmaxf(acc00[4 * q + 2], acc00[4 * q + 3]));
        float p1 = fmaxf(fmaxf(acc01[4 * q], acc01[4 * q + 1]),
                         fmaxf(acc01[4 * q + 2], acc01[4 * q + 3]));
        unsigned pk = cvtpk_bf16(fmaxf(p0 + bias0, 0.f), fmaxf(p1 + bias1, 0.f));
        poolg[(hf * 112 + lw0) * 64 + l31]      = (unsigned short)pk;
        poolg[(hf * 112 + lw0) * 64 + 32 + l31] = (unsigned short)(pk >> 16);
      }
      if (v1) {
        int lw1 = (wave + 8) * 8 + 2 * q + h;
        if (lw1 < Wh) {
          float p0 = fmaxf(fmaxf(acc10[4 * q], acc10[4 * q + 1]),
                           fmaxf(acc10[4 * q + 2], acc10[4 * q + 3]));
          float p1 = fmaxf(fmaxf(acc11[4 * q], acc11[4 * q + 1]),
                           fmaxf(acc11[4 * q + 2], acc11[4 * q + 3]));
          unsigned pk = cvtpk_bf16(fmaxf(p0 + bias0, 0.f), fmaxf(p1 + bias1, 0.f));
          poolg[(hf * 112 + lw1) * 64 + l31]      = (unsigned short)pk;
          poolg[(hf * 112 + lw1) * 64 + 32 + l31] = (unsigned short)(pk >> 16);
        }
      }
    }
  }
}

// ---------------- fc1 stage A: 256 blocks = 64 img-groups x 4 K-slices ----
// 8-deep B-prefetch ring (covers ~280cyc of L2 latency); over-reads past the
// q-slice end land in WFC2 region (benign, discarded).
__global__ __launch_bounds__(512) void fc1_kernel(unsigned short* __restrict__ ws16)
{
  extern __shared__ char smem[];
  short8* A8 = (short8*)smem;              // [16 img][393 short8] (stride pad)
  const int tid = threadIdx.x;
  const int wave = tid >> 6, lane = tid & 63;
  const int g = lane >> 4, l15 = lane & 15;
  const int ig = blockIdx.x >> 2, q = blockIdx.x & 3;
  const short8* pool8 = (const short8*)(ws16 + POOL_E);
  const short8* wf1 = (const short8*)(ws16 + WFC1_E);
  {
    int img = tid >> 5, l32 = tid & 31;
    const short8* src = pool8 + (ig * 16 + img) * 1568 + q * 392;
#pragma unroll
    for (int j = 0; j < 13; ++j) {
      int idx = l32 + 32 * j;
      if (idx < 392) A8[img * 393 + idx] = src[idx];
    }
  }
  __syncthreads();
  f32x4 accA = {0.f, 0.f, 0.f, 0.f}, accB = {0.f, 0.f, 0.f, 0.f};
  const short8* wbase = wf1 + (wave * 392 + q * 98) * 64 + lane;
  short8 b0 = wbase[0 * 64], b1 = wbase[1 * 64], b2 = wbase[2 * 64], b3 = wbase[3 * 64];
  short8 b4 = wbase[4 * 64], b5 = wbase[5 * 64], b6 = wbase[6 * 64], b7 = wbase[7 * 64];
#pragma unroll 1
  for (int c = 0; c < 12; ++c) {           // ks = 8c .. 8c+7 ; prefetch 8 ahead
    int ks = 8 * c;
    short8 a;
    a = A8[l15 * 393 + (ks + 0) * 4 + g];
    accA = __builtin_amdgcn_mfma_f32_16x16x32_bf16(a, b0, accA, 0, 0, 0);
    b0 = wbase[(ks + 8) * 64];
    a = A8[l15 * 393 + (ks + 1) * 4 + g];
    accB = __builtin_amdgcn_mfma_f32_16x16x32_bf16(a, b1, accB, 0, 0, 0);
    b1 = wbase[(ks + 9) * 64];
    a = A8[l15 * 393 + (ks + 2) * 4 + g];
    accA = __builtin_amdgcn_mfma_f32_16x16x32_bf16(a, b2, accA, 0, 0, 0);
    b2 = wbase[(ks + 10) * 64];
    a = A8[l15 * 393 + (ks + 3) * 4 + g];
    accB = __builtin_amdgcn_mfma_f32_16x16x32_bf16(a, b3, accB, 0, 0, 0);
    b3 = wbase[(ks + 11) * 64];
    a = A8[l15 * 393 + (ks + 4) * 4 + g];
    accA = __builtin_amdgcn_mfma_f32_16x16x32_bf16(a, b4, accA, 0, 0, 0);
    b4 = wbase[(ks + 12) * 64];
    a = A8[l15 * 393 + (ks + 5) * 4 + g];
    accB = __builtin_amdgcn_mfma_f32_16x16x32_bf16(a, b5, accB, 0, 0, 0);
    b5 = wbase[(ks + 13) * 64];
    a = A8[l15 * 393 + (ks + 6) * 4 + g];
    accA = __builtin_amdgcn_mfma_f32_16x16x32_bf16(a, b6, accA, 0, 0, 0);
    b6 = wbase[(ks + 14) * 64];
    a = A8[l15 * 393 + (ks + 7) * 4 + g];
    accB = __builtin_amdgcn_mfma_f32_16x16x32_bf16(a, b7, accB, 0, 0, 0);
    b7 = wbase[(ks + 15) * 64];
  }
  {                                        // tail ks = 96, 97 (b0 = 96, b1 = 97)
    short8 a;
    a = A8[l15 * 393 + 96 * 4 + g];
    accA = __builtin_amdgcn_mfma_f32_16x16x32_bf16(a, b0, accA, 0, 0, 0);
    a = A8[l15 * 393 + 97 * 4 + g];
    accB = __builtin_amdgcn_mfma_f32_16x16x32_bf16(a, b1, accB, 0, 0, 0);
  }
  _Float16* part = (_Float16*)((char*)ws16 + PART_B);
  int base = ((q * 64 + ig) * 16 + 4 * g) * 128 + wave * 16 + l15;
#pragma unroll
  for (int i = 0; i < 4; ++i) part[base + i * 128] = (_Float16)(accA[i] + accB[i]);
}

// ---------------- fc stage B: sum 4 partials + bias/relu + fc2 ----
__global__ __launch_bounds__(512) void fc2_kernel(
    const float* __restrict__ b1, const float* __restrict__ b2,
    const unsigned short* __restrict__ ws16, float* __restrict__ out)
{
  __shared__ unsigned short h_s[16 * 136];
  const int tid = threadIdx.x;
  const int wave = tid >> 6, lane = tid & 63;
  const int g = lane >> 4, l15 = lane & 15;
  const int ig = blockIdx.x;
  const _Float16* part = (const _Float16*)((const char*)ws16 + PART_B);
#pragma unroll
  for (int t = 0; t < 4; ++t) {
    int u = tid + 512 * t;
    int img = u >> 7, fcn = u & 127;
    float s = 0.f;
#pragma unroll
    for (int q2 = 0; q2 < 4; ++q2)
      s += (float)part[((q2 * 64 + ig) * 16 + img) * 128 + fcn];
    h_s[img * 136 + fcn] = f2bf(fmaxf(s + b1[fcn], 0.f));
  }
  __syncthreads();
  if (wave < 6) {
    const short8* wf2 = (const short8*)(ws16 + WFC2_E);
    const short8* h8 = (const short8*)h_s;
    f32x4 a2 = {0.f, 0.f, 0.f, 0.f};
#pragma unroll
    for (int ks = 0; ks < 4; ++ks) {
      short8 b = wf2[(wave * 4 + ks) * 64 + lane];
      short8 a = h8[l15 * 17 + ks * 4 + g];
      a2 = __builtin_amdgcn_mfma_f32_16x16x32_bf16(a, b, a2, 0, 0, 0);
    }
    int cls = wave * 16 + l15;
    if (cls < 83) {
      float bias2 = b2[cls];
#pragma unroll
      for (int i = 0; i < 4; ++i) {
        int nimg = ig * 16 + 4 * g + i;
        out[((nimg >> 5) * 83 + cls) * 32 + (nimg & 31)] = a2[i] + bias2;
      }
    }
  }
}

extern "C" void kernel_launch(void* const* d_in, const int* in_sizes, int n_in,
                              void* d_out, int out_size, void* d_ws, size_t ws_size,
                              hipStream_t stream)
{
  const float* x    = (const float*)d_in[0];
  const float* w1   = (const float*)d_in[1];
  const float* c1b  = (const float*)d_in[2];
  const float* w2   = (const float*)d_in[3];
  const float* c2b  = (const float*)d_in[4];
  const float* wfc1 = (const float*)d_in[5];
  const float* bfc1 = (const float*)d_in[6];
  const float* wfc2 = (const float*)d_in[7];
  const float* bfc2 = (const float*)d_in[8];
  unsigned short* ws16 = (unsigned short*)d_ws;
  float* out = (float*)d_out;

  prep_kernel<<<6472, 256, 0, stream>>>(w1, c1b, w2, wfc1, wfc2, ws16);
  conv_kernel<<<2048, 512, 79616, stream>>>(x, c2b, ws16);
  fc1_kernel<<<256, 512, 100608, stream>>>(ws16);
  fc2_kernel<<<64, 512, 0, stream>>>(bfc1, bfc2, ws16, out);
}

// Round 13
// 90.454 us; speedup vs baseline: 1.1314x; 1.0112x over previous
//
#include <hip/hip_runtime.h>
#include <hip/hip_bf16.h>

// LineCNNSimple: 1024 x (conv3x3 1->64 +relu, conv3x3 64->64 +relu, maxpool2,
// fc 12544->128 +relu, fc 128->83). bf16 MFMA pipeline.
// R13: R12 + (a) halo-only LDS zeroing in conv (interior fully overwritten by
//      conv1; pads never read); (b) prep wfc1 repack via LDS-tiled transpose
//      (coalesced reads AND writes; forward map line-amplified reads 2-3x).
//
// ws element(u16) offsets:
//   WB1  @0        : 2048    conv1 W frag [4nt][64lane][8], k==9 slot = bias
//   WB2  @2048     : 36864   conv2 W frag [2nh][36ks][64lane][8], k=(dy*3+dx)*64+ci
//   WFC1 @38912    : 1605632 fc1 W frag [8nt][392ks][64lane][8], k'=(oyp*14+oxp)*64+co
//   WFC2 @1644544  : 12288   fc2 W frag [6nt][4ks][64lane][8] (cls>=83 zeroed)
//   POOL @1656832  : 12845056 pooled acts [1024][12544] bf16 (k'-order)
//   PART @byte 29003776 : f16 fc1 partials [4q][64ig][16img][128fcn] (1MB)

typedef __attribute__((ext_vector_type(8))) short short8;
typedef __attribute__((ext_vector_type(4))) float f32x4;
typedef __attribute__((ext_vector_type(16))) float f32x16;

#define WB1_E   0u
#define WB2_E   2048u
#define WFC1_E  38912u
#define WFC2_E  1644544u
#define POOL_E  1656832u
#define PART_B  29003776u

__device__ __forceinline__ unsigned short f2bf(float f) {
  unsigned u = __float_as_uint(f);
  u += 0x7fffu + ((u >> 16) & 1u);   // round-to-nearest-even
  return (unsigned short)(u >> 16);
}
// pack two f32 -> bf16 pair (lo = a, hi = b), RNE, single instruction
__device__ __forceinline__ unsigned cvtpk_bf16(float a, float b) {
  unsigned r;
  asm("v_cvt_pk_bf16_f32 %0, %1, %2" : "=v"(r) : "v"(a), "v"(b));
  return r;
}

// ---------------- prep: repack weights to bf16 frag order ----------------
// blocks 0..111: wfc1 transpose via LDS tile (nt = b/14, 28-ks chunk = b%14).
// blocks 112..311: WB1 / WB2 / WFC2 forward map (small).
__global__ __launch_bounds__(256) void prep_kernel(
    const float* __restrict__ w1, const float* __restrict__ c1b,
    const float* __restrict__ w2, const float* __restrict__ wfc1,
    const float* __restrict__ wfc2, unsigned short* __restrict__ ws16)
{
  const int b = blockIdx.x, tid = threadIdx.x;
  if (b < 112) {
    __shared__ unsigned short T[14336];       // [f 16][co 64][sp 14] bf16
    const int nt = b / 14, ksc = b % 14;
    const float* src = wfc1 + nt * 16 * 12544 + 14 * ksc;
#pragma unroll
    for (int it = 0; it < 56; ++it) {         // 14336 = 56*256, contiguous runs
      int u = tid + 256 * it;
      int f = u / 896;
      int rem = u - f * 896;
      int co = rem / 14;
      int sp = rem - co * 14;
      T[u] = f2bf(src[f * 12544 + co * 196 + sp]);
    }
    __syncthreads();
    unsigned short* dst = ws16 + WFC1_E + (unsigned)(nt * 392 + 28 * ksc) * 512u;
#pragma unroll
    for (int it = 0; it < 7; ++it) {          // 1792 short8 = 7*256, coalesced
      int v = tid + 256 * it;
      int ksl = v >> 6, l = v & 63;
      int f15 = l & 15, g = l >> 4;
      int co0 = ((ksl & 1) << 5) + 8 * g;     // kp = (28ksc+ksl)*32+8g+j
      int spl = ksl >> 1;
      short8 o;
#pragma unroll
      for (int j = 0; j < 8; ++j)
        o[j] = (short)T[f15 * 896 + (co0 + j) * 14 + spl];
      *(short8*)(dst + v * 8) = o;
    }
  } else {
    int u = (b - 112) * 256 + tid;            // [0, 51200) exactly
    if (u < 2048) {
      int j = u & 7, l = (u >> 3) & 63, nt = u >> 9;
      int n = nt * 16 + (l & 15), k = 8 * (l >> 4) + j;
      float v = (k < 9) ? w1[n * 9 + k] : (k == 9 ? c1b[n] : 0.f);
      ws16[WB1_E + u] = f2bf(v);
    } else if (u < 38912) {
      int i2 = u - 2048;                      // conv2 W for 32x32x16 MFMA
      int j = i2 & 7, l = (i2 >> 3) & 63, rest = i2 >> 9;
      int ks = rest % 36, nh = rest / 36;
      int co = nh * 32 + (l & 31);
      int k = ks * 16 + (l >> 5) * 8 + j;
      int dydx = k >> 6, ci = k & 63;
      ws16[WB2_E + i2] = f2bf(w2[co * 576 + ci * 9 + dydx]);
    } else {
      int i2 = u - 38912;                     // wfc2 (zero-fills cls>=83)
      int j = i2 & 7, l = (i2 >> 3) & 63, rest = i2 >> 9;
      int ks = rest & 3, nt = rest >> 2;
      int cls = nt * 16 + (l & 15);
      int k = ks * 32 + 8 * (l >> 4) + j;
      float v = (cls < 83) ? wfc2[cls * 128 + k] : 0.f;
      ws16[WFC2_E + i2] = f2bf(v);
    }
  }
}

// ---------------- fused conv1+conv2+pool; one (image, row-half) per block ----
// lds1: [18 rows][30 cols] cells x 144 B (64 u16 co + 8 u16 pad) = 77,760 B
// xw:   padded 30x30 bf16 input @ 77760, 1800 B
__global__ __launch_bounds__(512, 4) void conv_kernel(
    const float* __restrict__ x, const float* __restrict__ c2b,
    unsigned short* __restrict__ ws16)
{
  extern __shared__ char smem[];
  unsigned short* xw = (unsigned short*)(smem + 77760);

  const int tid = threadIdx.x;
  const int wave = tid >> 6, lane = tid & 63;
  const int bid = blockIdx.x;
  const int n = bid >> 1, hf = bid & 1;
  const int rlo = hf ? 15 : 0;          // first conv1 output row this half
  const int M1 = hf ? 364 : 476;        // conv1 positions this half
  const int T1 = hf ? 23 : 30;          // conv1 16-tiles (ceil)
  const int lr_off = hf ? -15 : 1;      // conv1 store row: lr = rr + lr_off

  const short8* wb1 = (const short8*)(ws16 + WB1_E);
  unsigned short* poolg = ws16 + POOL_E + (unsigned)n * 12544u;

  short8 z8 = {0, 0, 0, 0, 0, 0, 0, 0};
  // zero ONLY the halo cells (64 cells x 8 short8 = 512 = one store/thread).
  // Interior cells are fully overwritten by conv1; 16B cell pads never read.
  // Stale never-read-path cells only affect masked-out output rows.
  {
    int cell = tid >> 3, e = tid & 7;
    int r, c;
    if (hf == 0) {                      // read rows 0..17, written 1..17 x 1..28
      if (cell < 30)      { r = 0;         c = cell; }
      else if (cell < 47) { r = cell - 29; c = 0; }
      else                { r = cell - 46; c = 29; }
    } else {                            // read rows 0..13, written 0..12 x 1..28
      if (cell < 30)      { r = 13;        c = cell; }
      else if (cell < 43) { r = cell - 30; c = 0; }
      else if (cell < 56) { r = cell - 43; c = 29; }
      else                { r = 13;        c = 0; }   // dup, harmless
    }
    *(short8*)(smem + ((r * 30 + c) * 144 + e * 16)) = z8;
    const float* xg = x + (n >> 5) * 25088 + (n & 31) * 28;
    for (int i = tid; i < 900; i += 512) {
      int yy = (i * 2185) >> 16;        // i/30
      int xx = i - yy * 30;
      int iy = yy - 1, ix = xx - 1;
      bool inb = (iy >= 0) && (iy < 28) && (ix >= 0) && (ix < 28);
      float v = inb ? xg[iy * 896 + ix] : 0.f;
      xw[i] = f2bf(v);
    }
  }
  __syncthreads();

  // ---- conv1 (16x16x32): weights as A-operand; compile-time LDS offsets
  {
    const int g = lane >> 4, l15 = lane & 15;
    short8 b1f[4];
#pragma unroll
    for (int nt = 0; nt < 4; ++nt) b1f[nt] = wb1[nt * 64 + lane];
    for (int mt = wave; mt < T1; mt += 8) {
      int m = mt * 16 + l15;
      bool mval = m < M1;
      int mc = mval ? m : M1 - 1;
      int yr = (mc * 2341) >> 16;       // mc/28
      int rr = rlo + yr;
      int ox = mc - yr * 28;
      const char* xb = (const char*)xw + (rr * 30 + ox) * 2;
      short8 a = z8;
      if (g == 0) {                     // k = 0..7  (dy*3+dx)
        a[0] = *(const short*)(xb + 0);
        a[1] = *(const short*)(xb + 2);
        a[2] = *(const short*)(xb + 4);
        a[3] = *(const short*)(xb + 60);
        a[4] = *(const short*)(xb + 62);
        a[5] = *(const short*)(xb + 64);
        a[6] = *(const short*)(xb + 120);
        a[7] = *(const short*)(xb + 122);
      } else if (g == 1) {              // k = 8, k = 9 bias lane
        a[0] = *(const short*)(xb + 124);
        a[1] = (short)0x3F80;           // 1.0 bf16
      }
      f32x4 d[4];
#pragma unroll
      for (int nt = 0; nt < 4; ++nt) {
        f32x4 zz = {0.f, 0.f, 0.f, 0.f};
        d[nt] = __builtin_amdgcn_mfma_f32_16x16x32_bf16(b1f[nt], a, zz, 0, 0, 0);
      }
      if (mval) {                       // D: row=co 4g+i, col=own l15 -> m
        int spB = ((rr + lr_off) * 30 + ox + 1) * 144;
#pragma unroll
        for (int nt = 0; nt < 4; ++nt) {
          float r0 = fmaxf(d[nt][0], 0.f), r1 = fmaxf(d[nt][1], 0.f);
          float r2 = fmaxf(d[nt][2], 0.f), r3 = fmaxf(d[nt][3], 0.f);
          int co2 = nt * 16 + 4 * g;
          *(unsigned*)(smem + (spB + co2 * 2)) = cvtpk_bf16(r0, r1);
          *(unsigned*)(smem + (spB + co2 * 2 + 4)) = cvtpk_bf16(r2, r3);
        }
      }
    }
  }
  __syncthreads();

  // ---- conv2 (32x32x16): wave owns tiles (wave, wave+8) x both co-halves.
  // Raw s_barrier per phase-pair aligns all 8 waves' B-loads (L1 sharing).
  {
    const int l31 = lane & 31;
    const int h = lane >> 5;
    const int T32 = hf ? 11 : 14;       // M-tiles this half
    const int Wh  = hf ? 84 : 112;      // valid windows this half
    const float bias0 = c2b[l31];
    const float bias1 = c2b[32 + l31];
    const short8* wb2w = (const short8*)(ws16 + WB2_E) + lane;

    const bool v1 = (wave + 8) < T32;
    int baseB0, baseB1;
    {
      int lw = wave * 8 + (l31 >> 2);
      int py = lw / 14, px = lw % 14;
      baseB0 = ((2 * py + ((l31 >> 1) & 1)) * 30 + 2 * px + (l31 & 1)) * 144 + h * 16;
      int tI1 = v1 ? (wave + 8) : wave;  // clamp (unused when !v1)
      int lw1 = tI1 * 8 + (l31 >> 2);
      int py1 = lw1 / 14, px1 = lw1 % 14;
      baseB1 = ((2 * py1 + ((l31 >> 1) & 1)) * 30 + 2 * px1 + (l31 & 1)) * 144 + h * 16;
    }
    f32x16 acc00 = (f32x16)(0.0f), acc01 = (f32x16)(0.0f);
    f32x16 acc10 = (f32x16)(0.0f), acc11 = (f32x16)(0.0f);

    short8 bfA0, bfA1, bfA2, bfA3;      // ping (nh0 k0, nh0 k1, nh1 k0, nh1 k1)
    short8 bfB0, bfB1, bfB2, bfB3;      // pong

#define LOADB(d0, d1, d2, d3, hp) do {                                   \
      const int ph_ = (hp) >> 1, k0_ = ((hp) & 1) * 2;                   \
      d0 = wb2w[(ph_ * 4 + k0_) * 64];                                   \
      d1 = wb2w[(ph_ * 4 + k0_ + 1) * 64];                               \
      d2 = wb2w[2304 + (ph_ * 4 + k0_) * 64];                            \
      d3 = wb2w[2304 + (ph_ * 4 + k0_ + 1) * 64];                        \
    } while (0)
#define COMPT(hp, base, aL, aH, b0, b1, b2, b3) do {                     \
      const int ph_ = (hp) >> 1, k0_ = ((hp) & 1) * 2;                   \
      const int cell_ = ((ph_ / 3) * 30 + (ph_ % 3)) * 144 + 32 * k0_;   \
      short8 a0 = *(const short8*)(smem + (base + cell_));               \
      short8 a1 = *(const short8*)(smem + (base + cell_ + 32));          \
      aL = __builtin_amdgcn_mfma_f32_32x32x16_bf16(a0, b0, aL, 0, 0, 0); \
      aH = __builtin_amdgcn_mfma_f32_32x32x16_bf16(a0, b2, aH, 0, 0, 0); \
      aL = __builtin_amdgcn_mfma_f32_32x32x16_bf16(a1, b1, aL, 0, 0, 0); \
      aH = __builtin_amdgcn_mfma_f32_32x32x16_bf16(a1, b3, aH, 0, 0, 0); \
    } while (0)

    LOADB(bfA0, bfA1, bfA2, bfA3, 0);
    if (v1) {
#pragma unroll
      for (int hp = 0; hp < 18; hp += 2) {
        __builtin_amdgcn_s_barrier();   // align waves' B-loads (no waitcnt)
        if (hp + 1 < 18) LOADB(bfB0, bfB1, bfB2, bfB3, hp + 1);
        COMPT(hp, baseB0, acc00, acc01, bfA0, bfA1, bfA2, bfA3);
        COMPT(hp, baseB1, acc10, acc11, bfA0, bfA1, bfA2, bfA3);
        if (hp + 2 < 18) LOADB(bfA0, bfA1, bfA2, bfA3, hp + 2);
        COMPT(hp + 1, baseB0, acc00, acc01, bfB0, bfB1, bfB2, bfB3);
        COMPT(hp + 1, baseB1, acc10, acc11, bfB0, bfB1, bfB2, bfB3);
      }
    } else {
#pragma unroll
      for (int hp = 0; hp < 18; hp += 2) {
        __builtin_amdgcn_s_barrier();
        if (hp + 1 < 18) LOADB(bfB0, bfB1, bfB2, bfB3, hp + 1);
        COMPT(hp, baseB0, acc00, acc01, bfA0, bfA1, bfA2, bfA3);
        if (hp + 2 < 18) LOADB(bfA0, bfA1, bfA2, bfA3, hp + 2);
        COMPT(hp + 1, baseB0, acc00, acc01, bfB0, bfB1, bfB2, bfB3);
      }
    }
#undef LOADB
#undef COMPT

    // epilogue: 2x2 max + bias + relu -> global (bf16, fc1 k'-order)
#pragma unroll
    for (int q = 0; q < 4; ++q) {
      int lw0 = wave * 8 + 2 * q + h;
      {
        float p0 = fmaxf(fmaxf(acc00[4 * q], acc00[4 * q + 1]),
                         fmaxf(acc00[4 * q + 2], acc00[4 * q + 3]));
        float p1 = fmaxf(fmaxf(acc01[4 * q], acc01[4 * q + 1]),
                         fmaxf(acc01[4 * q + 2], acc01[4 * q + 3]));
        unsigned pk = cvtpk_bf16(fmaxf(p0 + bias0, 0.f), fmaxf(p1 + bias1, 0.f));
        poolg[(hf * 112 + lw0) * 64 + l31]      = (unsigned short)pk;
        poolg[(hf * 112 + lw0) * 64 + 32 + l31] = (unsigned short)(pk >> 16);
      }
      if (v1) {
        int lw1 = (wave + 8) * 8 + 2 * q + h;
        if (lw1 < Wh) {
          float p0 = fmaxf(fmaxf(acc10[4 * q], acc10[4 * q + 1]),
                           fmaxf(acc10[4 * q + 2], acc10[4 * q + 3]));
          float p1 = fmaxf(fmaxf(acc11[4 * q], acc11[4 * q + 1]),
                           fmaxf(acc11[4 * q + 2], acc11[4 * q + 3]));
          unsigned pk = cvtpk_bf16(fmaxf(p0 + bias0, 0.f), fmaxf(p1 + bias1, 0.f));
          poolg[(hf * 112 + lw1) * 64 + l31]      = (unsigned short)pk;
          poolg[(hf * 112 + lw1) * 64 + 32 + l31] = (unsigned short)(pk >> 16);
        }
      }
    }
  }
}

// ---------------- fc1 stage A: 256 blocks = 64 img-groups x 4 K-slices ----
// 8-deep B-prefetch ring; over-reads past the q-slice end land in WFC2
// region (benign, discarded).
__global__ __launch_bounds__(512) void fc1_kernel(unsigned short* __restrict__ ws16)
{
  extern __shared__ char smem[];
  short8* A8 = (short8*)smem;              // [16 img][393 short8] (stride pad)
  const int tid = threadIdx.x;
  const int wave = tid >> 6, lane = tid & 63;
  const int g = lane >> 4, l15 = lane & 15;
  const int ig = blockIdx.x >> 2, q = blockIdx.x & 3;
  const short8* pool8 = (const short8*)(ws16 + POOL_E);
  const short8* wf1 = (const short8*)(ws16 + WFC1_E);
  {
    int img = tid >> 5, l32 = tid & 31;
    const short8* src = pool8 + (ig * 16 + img) * 1568 + q * 392;
#pragma unroll
    for (int j = 0; j < 13; ++j) {
      int idx = l32 + 32 * j;
      if (idx < 392) A8[img * 393 + idx] = src[idx];
    }
  }
  __syncthreads();
  f32x4 accA = {0.f, 0.f, 0.f, 0.f}, accB = {0.f, 0.f, 0.f, 0.f};
  const short8* wbase = wf1 + (wave * 392 + q * 98) * 64 + lane;
  short8 b0 = wbase[0 * 64], b1 = wbase[1 * 64], b2 = wbase[2 * 64], b3 = wbase[3 * 64];
  short8 b4 = wbase[4 * 64], b5 = wbase[5 * 64], b6 = wbase[6 * 64], b7 = wbase[7 * 64];
#pragma unroll 1
  for (int c = 0; c < 12; ++c) {           // ks = 8c .. 8c+7 ; prefetch 8 ahead
    int ks = 8 * c;
    short8 a;
    a = A8[l15 * 393 + (ks + 0) * 4 + g];
    accA = __builtin_amdgcn_mfma_f32_16x16x32_bf16(a, b0, accA, 0, 0, 0);
    b0 = wbase[(ks + 8) * 64];
    a = A8[l15 * 393 + (ks + 1) * 4 + g];
    accB = __builtin_amdgcn_mfma_f32_16x16x32_bf16(a, b1, accB, 0, 0, 0);
    b1 = wbase[(ks + 9) * 64];
    a = A8[l15 * 393 + (ks + 2) * 4 + g];
    accA = __builtin_amdgcn_mfma_f32_16x16x32_bf16(a, b2, accA, 0, 0, 0);
    b2 = wbase[(ks + 10) * 64];
    a = A8[l15 * 393 + (ks + 3) * 4 + g];
    accB = __builtin_amdgcn_mfma_f32_16x16x32_bf16(a, b3, accB, 0, 0, 0);
    b3 = wbase[(ks + 11) * 64];
    a = A8[l15 * 393 + (ks + 4) * 4 + g];
    accA = __builtin_amdgcn_mfma_f32_16x16x32_bf16(a, b4, accA, 0, 0, 0);
    b4 = wbase[(ks + 12) * 64];
    a = A8[l15 * 393 + (ks + 5) * 4 + g];
    accB = __builtin_amdgcn_mfma_f32_16x16x32_bf16(a, b5, accB, 0, 0, 0);
    b5 = wbase[(ks + 13) * 64];
    a = A8[l15 * 393 + (ks + 6) * 4 + g];
    accA = __builtin_amdgcn_mfma_f32_16x16x32_bf16(a, b6, accA, 0, 0, 0);
    b6 = wbase[(ks + 14) * 64];
    a = A8[l15 * 393 + (ks + 7) * 4 + g];
    accB = __builtin_amdgcn_mfma_f32_16x16x32_bf16(a, b7, accB, 0, 0, 0);
    b7 = wbase[(ks + 15) * 64];
  }
  {                                        // tail ks = 96, 97
    short8 a;
    a = A8[l15 * 393 + 96 * 4 + g];
    accA = __builtin_amdgcn_mfma_f32_16x16x32_bf16(a, b0, accA, 0, 0, 0);
    a = A8[l15 * 393 + 97 * 4 + g];
    accB = __builtin_amdgcn_mfma_f32_16x16x32_bf16(a, b1, accB, 0, 0, 0);
  }
  _Float16* part = (_Float16*)((char*)ws16 + PART_B);
  int base = ((q * 64 + ig) * 16 + 4 * g) * 128 + wave * 16 + l15;
#pragma unroll
  for (int i = 0; i < 4; ++i) part[base + i * 128] = (_Float16)(accA[i] + accB[i]);
}

// ---------------- fc stage B: sum 4 partials + bias/relu + fc2 ----
__global__ __launch_bounds__(512) void fc2_kernel(
    const float* __restrict__ b1, const float* __restrict__ b2,
    const unsigned short* __restrict__ ws16, float* __restrict__ out)
{
  __shared__ unsigned short h_s[16 * 136];
  const int tid = threadIdx.x;
  const int wave = tid >> 6, lane = tid & 63;
  const int g = lane >> 4, l15 = lane & 15;
  const int ig = blockIdx.x;
  const _Float16* part = (const _Float16*)((const char*)ws16 + PART_B);
#pragma unroll
  for (int t = 0; t < 4; ++t) {
    int u = tid + 512 * t;
    int img = u >> 7, fcn = u & 127;
    float s = 0.f;
#pragma unroll
    for (int q2 = 0; q2 < 4; ++q2)
      s += (float)part[((q2 * 64 + ig) * 16 + img) * 128 + fcn];
    h_s[img * 136 + fcn] = f2bf(fmaxf(s + b1[fcn], 0.f));
  }
  __syncthreads();
  if (wave < 6) {
    const short8* wf2 = (const short8*)(ws16 + WFC2_E);
    const short8* h8 = (const short8*)h_s;
    f32x4 a2 = {0.f, 0.f, 0.f, 0.f};
#pragma unroll
    for (int ks = 0; ks < 4; ++ks) {
      short8 b = wf2[(wave * 4 + ks) * 64 + lane];
      short8 a = h8[l15 * 17 + ks * 4 + g];
      a2 = __builtin_amdgcn_mfma_f32_16x16x32_bf16(a, b, a2, 0, 0, 0);
    }
    int cls = wave * 16 + l15;
    if (cls < 83) {
      float bias2 = b2[cls];
#pragma unroll
      for (int i = 0; i < 4; ++i) {
        int nimg = ig * 16 + 4 * g + i;
        out[((nimg >> 5) * 83 + cls) * 32 + (nimg & 31)] = a2[i] + bias2;
      }
    }
  }
}

extern "C" void kernel_launch(void* const* d_in, const int* in_sizes, int n_in,
                              void* d_out, int out_size, void* d_ws, size_t ws_size,
                              hipStream_t stream)
{
  const float* x    = (const float*)d_in[0];
  const float* w1   = (const float*)d_in[1];
  const float* c1b  = (const float*)d_in[2];
  const float* w2   = (const float*)d_in[3];
  const float* c2b  = (const float*)d_in[4];
  const float* wfc1 = (const float*)d_in[5];
  const float* bfc1 = (const float*)d_in[6];
  const float* wfc2 = (const float*)d_in[7];
  const float* bfc2 = (const float*)d_in[8];
  unsigned short* ws16 = (unsigned short*)d_ws;
  float* out = (float*)d_out;

  prep_kernel<<<312, 256, 0, stream>>>(w1, c1b, w2, wfc1, wfc2, ws16);
  conv_kernel<<<2048, 512, 79616, stream>>>(x, c2b, ws16);
  fc1_kernel<<<256, 512, 100608, stream>>>(ws16);
  fc2_kernel<<<64, 512, 0, stream>>>(bfc1, bfc2, ws16, out);
}